// Round 5
// baseline (146.957 us; speedup 1.0000x reference)
//
#include <hip/hip_runtime.h>

// OrdLoss: N=2, C=16, D=32, H=128, W=128
// out = [ sum_{valid m} ( sum_{c<=t} log(clip(p)) + sum_{c>t} log(clip(1-p)) ) ] / ( -sum(valid) )
//
// R5: minimal streaming pass. Evidence from R2-R4: bench dur_us is pinned at
// ~137 +- 4 across radically different kernel structures; the profile is
// dominated by harness restore/poison dispatches (268 MB d_ws fill = 41 us,
// 3 input restores ~45 us) -> fixed floor ~110-125 us. What's left for us:
// run the 76 MB sweep at the streaming roofline (~12 us) with max occupancy
// (2048 blocks x 256 thr = 32 waves/CU), grid-stride so every load of every
// lane is 16 B contiguous, and make the final reduce featherweight (12 KB).

constexpr int kC     = 16;
constexpr int kDHW   = 32 * 128 * 128;    // 524288 = 2^19
constexpr int kBlock = 256;
constexpr int kGrid  = 2048;              // 8192 waves = 32/CU = full occupancy
constexpr int kIter  = 8;                 // 2048*256*8 float4 = 2^22 = all of pred
constexpr int kLanes = kGrid * kBlock;    // 524288

__global__ __launch_bounds__(kBlock)
void ordloss_main(const float* __restrict__ pred,
                  const int*   __restrict__ target,
                  const int*   __restrict__ mask,
                  float*       __restrict__ bsum,
                  int*         __restrict__ bcnt) {
    const int lane0 = blockIdx.x * kBlock + threadIdx.x;

    float acc0 = 0.f, acc1 = 0.f, acc2 = 0.f, acc3 = 0.f;
    int   lcnt = 0;

    #pragma unroll
    for (int i = 0; i < kIter; ++i) {
        const int f  = (i * kLanes + lane0) * 4;    // flat pred element index
        const int n  = f >> 23;                     // sample      (block-uniform)
        const int c  = (f >> 19) & 15;              // channel     (block-uniform)
        const int sp = f & (kDHW - 1);              // spatial offset

        const float4 p  = *reinterpret_cast<const float4*>(pred + f);
        const int4   tg = *reinterpret_cast<const int4*>(target + ((size_t)n << 23) + sp);
        const int4   mk = *reinterpret_cast<const int4*>(mask + ((size_t)n << 19) + sp);

        const float x0 = (c <= tg.x) ? p.x : 1.0f - p.x;
        const float x1 = (c <= tg.y) ? p.y : 1.0f - p.y;
        const float x2 = (c <= tg.z) ? p.z : 1.0f - p.z;
        const float x3 = (c <= tg.w) ? p.w : 1.0f - p.w;
        acc0 += (mk.x > 0) ? __logf(fmaxf(x0, 1e-8f)) : 0.f;  // p in [0,1): lower clip only
        acc1 += (mk.y > 0) ? __logf(fmaxf(x1, 1e-8f)) : 0.f;
        acc2 += (mk.z > 0) ? __logf(fmaxf(x2, 1e-8f)) : 0.f;
        acc3 += (mk.w > 0) ? __logf(fmaxf(x3, 1e-8f)) : 0.f;
        if (c == 0)  // each voxel is seen with c==0 by exactly one lane-slot
            lcnt += (mk.x > 0) + (mk.y > 0) + (mk.z > 0) + (mk.w > 0);
    }

    float lsum = (acc0 + acc1) + (acc2 + acc3);
    #pragma unroll
    for (int off = 32; off > 0; off >>= 1) {
        lsum += __shfl_down(lsum, off);
        lcnt += __shfl_down(lcnt, off);
    }
    __shared__ float swave[kBlock / 64];
    __shared__ int   cwave[kBlock / 64];
    const int lane = threadIdx.x & 63;
    const int wid  = threadIdx.x >> 6;
    if (lane == 0) { swave[wid] = lsum; cwave[wid] = lcnt; }
    __syncthreads();
    if (threadIdx.x == 0) {
        bsum[blockIdx.x] = swave[0] + swave[1] + swave[2] + swave[3];
        bcnt[blockIdx.x] = cwave[0] + cwave[1] + cwave[2] + cwave[3];
    }
}

// 1 block, 256 threads: reduce 2048 float partials + 2048 int counts (12 KB).
__global__ __launch_bounds__(kBlock)
void ordloss_reduce(const float* __restrict__ bsum,
                    const int*   __restrict__ bcnt,
                    float*       __restrict__ out) {
    double s = 0.0;
    long   c = 0;
    #pragma unroll
    for (int j = 0; j < 2; ++j) {
        const float4 v  = *reinterpret_cast<const float4*>(bsum + (j * kBlock + threadIdx.x) * 4);
        const int4   c4 = *reinterpret_cast<const int4*>(bcnt + (j * kBlock + threadIdx.x) * 4);
        s += (double)v.x + v.y + v.z + v.w;
        c += (long)c4.x + c4.y + c4.z + c4.w;
    }
    #pragma unroll
    for (int off = 32; off > 0; off >>= 1) {
        s += __shfl_down(s, off);
        c += __shfl_down(c, off);
    }
    __shared__ double sw[kBlock / 64];
    __shared__ long   cw[kBlock / 64];
    const int lane = threadIdx.x & 63;
    const int wid  = threadIdx.x >> 6;
    if (lane == 0) { sw[wid] = s; cw[wid] = c; }
    __syncthreads();
    if (threadIdx.x == 0) {
        double S = sw[0] + sw[1] + sw[2] + sw[3];
        long   C = cw[0] + cw[1] + cw[2] + cw[3];
        out[0] = (float)(S / (double)(-C));
    }
}

extern "C" void kernel_launch(void* const* d_in, const int* in_sizes, int n_in,
                              void* d_out, int out_size, void* d_ws, size_t ws_size,
                              hipStream_t stream) {
    const float* pred   = (const float*)d_in[0];
    const int*   target = (const int*)d_in[1];
    const int*   mask   = (const int*)d_in[2];
    float*       bsum   = (float*)d_ws;                               // 2048 floats
    int*         bcnt   = (int*)((char*)d_ws + kGrid * sizeof(float)); // 2048 ints
    float*       out    = (float*)d_out;

    ordloss_main<<<kGrid, kBlock, 0, stream>>>(pred, target, mask, bsum, bcnt);
    ordloss_reduce<<<1, kBlock, 0, stream>>>(bsum, bcnt, out);
}

// Round 6
// 135.477 us; speedup vs baseline: 1.0847x; 1.0847x over previous
//
#include <hip/hip_runtime.h>

// OrdLoss: N=2, C=16, D=32, H=128, W=128
// out = [ sum_{valid m} ( sum_{c<=t} log(clip(p)) + sum_{c>t} log(clip(1-p)) ) ] / ( -sum(valid) )
//
// FINAL (revert to best-measured R2 structure, 137.2 us):
// Session record: four structurally different kernels (R2 prefetch / R3
// +sched_barrier / R4 transpose / R5 grid-stride) measured 137.2 / 137.3 /
// 141.6 / 147.0 us. Profile top-5 is always harness poison fills (268 MB,
// 41 us, 82% HBM peak); harness restore+poison traffic accounts for
// ~110-125 us of every timed iteration. Kernel share ~15-25 us vs a ~15 us
// compulsory-traffic floor (76 MB: pred 64 MiB + target ch0 4 MiB + mask
// 8 MiB, at ~6.3 TB/s). Remaining kernel headroom is below session noise.
//
// Structure: 1024 blocks x 256 threads, 4 voxels/thread. All 18 loads
// (16 pred float4 @ 2 MiB channel stride + target-ch0 int4 + mask int4)
// issued before compute; 64 logs over 4 independent accumulator chains;
// wave64 shuffle reduce -> LDS -> one plain store per block; 1-block
// reduce kernel folds 1024 partials in double and writes s / (-S).

constexpr int  kC     = 16;
constexpr int  kDHW   = 32 * 128 * 128;   // 524288 = 2^19
constexpr long kM     = 2L * kDHW;        // 1048576 voxels
constexpr int  kBlock = 256;
constexpr int  kVox   = 4;                // voxels per thread (one float4 per channel)
constexpr int  kGrid  = (int)(kM / kVox / kBlock);   // 1024 blocks

__global__ __launch_bounds__(kBlock)
void ordloss_main(const float* __restrict__ pred,
                  const int*   __restrict__ target,
                  const int*   __restrict__ mask,
                  float*       __restrict__ bsum,
                  int*         __restrict__ bcnt) {
    const int  tid  = blockIdx.x * kBlock + threadIdx.x;
    const long base = (long)tid * kVox;
    const int  n    = (int)(base >> 19);             // base / kDHW
    const int  sp   = (int)(base & (kDHW - 1));

    // ---- issue ALL loads up front ----
    const int4 mk = *reinterpret_cast<const int4*>(mask + base);
    const int4 tg = *reinterpret_cast<const int4*>(target + ((size_t)n << 23) + sp);
    const float* pb = pred + ((size_t)n << 23) + sp; // n*16*kDHW
    float4 p[kC];
    #pragma unroll
    for (int c = 0; c < kC; ++c)
        p[c] = *reinterpret_cast<const float4*>(pb + ((size_t)c << 19));

    // ---- compute: 64 logs, 4 independent accumulator chains ----
    float acc0 = 0.f, acc1 = 0.f, acc2 = 0.f, acc3 = 0.f;
    #pragma unroll
    for (int c = 0; c < kC; ++c) {
        float x0 = (c <= tg.x) ? p[c].x : 1.0f - p[c].x;
        float x1 = (c <= tg.y) ? p[c].y : 1.0f - p[c].y;
        float x2 = (c <= tg.z) ? p[c].z : 1.0f - p[c].z;
        float x3 = (c <= tg.w) ? p[c].w : 1.0f - p[c].w;
        acc0 += __logf(fmaxf(x0, 1e-8f));   // p in [0,1): only the lower clip binds
        acc1 += __logf(fmaxf(x1, 1e-8f));
        acc2 += __logf(fmaxf(x2, 1e-8f));
        acc3 += __logf(fmaxf(x3, 1e-8f));
    }

    float lsum = (mk.x > 0 ? acc0 : 0.f) + (mk.y > 0 ? acc1 : 0.f)
               + (mk.z > 0 ? acc2 : 0.f) + (mk.w > 0 ? acc3 : 0.f);
    int   lcnt = (mk.x > 0) + (mk.y > 0) + (mk.z > 0) + (mk.w > 0);

    // ---- wave64 reduce, then LDS, then one plain store per block ----
    #pragma unroll
    for (int off = 32; off > 0; off >>= 1) {
        lsum += __shfl_down(lsum, off);
        lcnt += __shfl_down(lcnt, off);
    }
    __shared__ float swave[kBlock / 64];
    __shared__ int   cwave[kBlock / 64];
    const int lane = threadIdx.x & 63;
    const int wid  = threadIdx.x >> 6;
    if (lane == 0) { swave[wid] = lsum; cwave[wid] = lcnt; }
    __syncthreads();
    if (threadIdx.x == 0) {
        bsum[blockIdx.x] = swave[0] + swave[1] + swave[2] + swave[3];
        bcnt[blockIdx.x] = cwave[0] + cwave[1] + cwave[2] + cwave[3];
    }
}

// 1 block, 256 threads: reduce 1024 partials, write the scalar.
__global__ __launch_bounds__(kBlock)
void ordloss_reduce(const float* __restrict__ bsum,
                    const int*   __restrict__ bcnt,
                    float*       __restrict__ out) {
    const float4 s4 = *reinterpret_cast<const float4*>(bsum + threadIdx.x * 4);
    const int4   c4 = *reinterpret_cast<const int4*>(bcnt + threadIdx.x * 4);
    double s = (double)s4.x + s4.y + s4.z + s4.w;
    long   c = (long)c4.x + c4.y + c4.z + c4.w;
    #pragma unroll
    for (int off = 32; off > 0; off >>= 1) {
        s += __shfl_down(s, off);
        c += __shfl_down(c, off);
    }
    __shared__ double sw[kBlock / 64];
    __shared__ long   cw[kBlock / 64];
    const int lane = threadIdx.x & 63;
    const int wid  = threadIdx.x >> 6;
    if (lane == 0) { sw[wid] = s; cw[wid] = c; }
    __syncthreads();
    if (threadIdx.x == 0) {
        double S = sw[0] + sw[1] + sw[2] + sw[3];
        long   C = cw[0] + cw[1] + cw[2] + cw[3];
        out[0] = (float)(S / (double)(-C));
    }
}

extern "C" void kernel_launch(void* const* d_in, const int* in_sizes, int n_in,
                              void* d_out, int out_size, void* d_ws, size_t ws_size,
                              hipStream_t stream) {
    const float* pred   = (const float*)d_in[0];
    const int*   target = (const int*)d_in[1];
    const int*   mask   = (const int*)d_in[2];
    float*       bsum   = (float*)d_ws;               // 1024 floats
    int*         bcnt   = (int*)((char*)d_ws + kGrid * sizeof(float)); // 1024 ints
    float*       out    = (float*)d_out;

    ordloss_main<<<kGrid, kBlock, 0, stream>>>(pred, target, mask, bsum, bcnt);
    ordloss_reduce<<<1, kBlock, 0, stream>>>(bsum, bcnt, out);
}